// Round 10
// baseline (729.446 us; speedup 1.0000x reference)
//
#include <hip/hip_runtime.h>

#define NROWS 1048576
#define DIM   128
#define NCLS  1000
#define NBLK  256           // hist/scatter blocks
#define RPB   4096          // rows per block in hist/scatter (NROWS/NBLK)
#define RPT   16            // rows per thread (RPB/256)
#define MOM   0.95f

// ws layout (u32):
//   total[1024] | classBase[1024] | blockCnt[256*1024] | blockBase[256*1024]
//   | perm[NROWS]   (~6.3 MB total; only total[] needs zeroing per call)

// ---------------------------------------------------------------------------
// K1: per-block LDS histogram -> blockCnt[b][c] and global total[c]
// ---------------------------------------------------------------------------
__global__ __launch_bounds__(256) void k_hist(const int* __restrict__ labels,
                                              unsigned* __restrict__ total,
                                              unsigned* __restrict__ blockCnt)
{
    __shared__ unsigned h[NCLS];
    const int tid = threadIdx.x;
    const int b   = blockIdx.x;
    for (int c = tid; c < NCLS; c += 256) h[c] = 0u;
    __syncthreads();
    const int base = b * RPB;
#pragma unroll
    for (int k = 0; k < RPT; ++k)
        atomicAdd(&h[labels[base + k * 256 + tid]], 1u);
    __syncthreads();
    for (int c = tid; c < NCLS; c += 256) {
        const unsigned cnt = h[c];
        blockCnt[b * 1024 + c] = cnt;
        if (cnt) atomicAdd(&total[c], cnt);
    }
}

// ---------------------------------------------------------------------------
// K2: single-block exclusive scan over total -> classBase
// ---------------------------------------------------------------------------
__global__ __launch_bounds__(1024) void k_scan(const unsigned* __restrict__ total,
                                               unsigned* __restrict__ classBase)
{
    __shared__ unsigned s[1024];
    const int tid = threadIdx.x;
    unsigned v = (tid < NCLS) ? total[tid] : 0u;
    s[tid] = v;
    __syncthreads();
    for (int off = 1; off < 1024; off <<= 1) {
        unsigned u = (tid >= off) ? s[tid - off] : 0u;
        __syncthreads();
        s[tid] += u;
        __syncthreads();
    }
    if (tid < NCLS) classBase[tid] = s[tid] - v;   // exclusive prefix
}

// ---------------------------------------------------------------------------
// K2b: per-class scan across the 256 hist blocks ->
//      blockBase[b][c] = classBase[c] + sum_{b'<b} blockCnt[b'][c]
//      grid = NCLS blocks, 256 threads (thread t owns hist-block t).
// ---------------------------------------------------------------------------
__global__ __launch_bounds__(256) void k_scanB(const unsigned* __restrict__ blockCnt,
                                               const unsigned* __restrict__ classBase,
                                               unsigned* __restrict__ blockBase)
{
    __shared__ unsigned s[256];
    const int c = blockIdx.x;
    const int t = threadIdx.x;
    unsigned v = blockCnt[t * 1024 + c];
    s[t] = v;
    __syncthreads();
    for (int off = 1; off < 256; off <<= 1) {
        unsigned u = (t >= off) ? s[t - off] : 0u;
        __syncthreads();
        s[t] += u;
        __syncthreads();
    }
    blockBase[t * 1024 + c] = classBase[c] + (s[t] - v);
}

// ---------------------------------------------------------------------------
// K3: scatter. Bases are precomputed (no global atomics); per-element
// offsets via LDS atomic-return. perm[pos] = row index, grouped by class.
// ---------------------------------------------------------------------------
__global__ __launch_bounds__(256) void k_scatter(const int* __restrict__ labels,
                                                 const unsigned* __restrict__ blockBase,
                                                 unsigned* __restrict__ perm)
{
    __shared__ unsigned off_lds[NCLS];
    __shared__ unsigned basec[NCLS];
    const int tid = threadIdx.x;
    const int b   = blockIdx.x;
    for (int c = tid; c < NCLS; c += 256) {
        basec[c]   = blockBase[b * 1024 + c];
        off_lds[c] = 0u;
    }
    __syncthreads();
    const int base = b * RPB;
#pragma unroll
    for (int k = 0; k < RPT; ++k) {
        const int r = base + k * 256 + tid;
        const int c = labels[r];
        unsigned o = atomicAdd(&off_lds[c], 1u);
        perm[basec[c] + o] = (unsigned)r;
    }
}

// ---------------------------------------------------------------------------
// K4: one block (512 thr, 16 row-groups) per class. Gather rows via perm
// (contiguous 512B per row, 32 lanes x float4), 8 independent load chains
// per thread, register accumulate, LDS tree reduce, fused EMA epilogue.
// ---------------------------------------------------------------------------
__global__ __launch_bounds__(512) void k_reduce(
        const float*    __restrict__ feats,
        const float*    __restrict__ weights,
        const float*    __restrict__ proto,
        const unsigned* __restrict__ perm,
        const unsigned* __restrict__ total,
        const unsigned* __restrict__ classBase,
        float* __restrict__ out)
{
    const int c      = blockIdx.x;
    const int tid    = threadIdx.x;
    const int lane32 = tid & 31;
    const int grp    = tid >> 5;            // 0..15 row-groups
    const int n      = (int)total[c];
    const unsigned base = classBase[c];
    const float4* __restrict__ f4 = (const float4*)feats;

    float4 acc = make_float4(0.f, 0.f, 0.f, 0.f);
    float  wacc = 0.f;

    int i = grp;
    // 8 independent perm->weights/feats chains in flight per thread
    for (; i + 112 < n; i += 128) {
        unsigned r[8]; float w[8]; float4 f[8];
#pragma unroll
        for (int u = 0; u < 8; ++u) r[u] = perm[base + i + u * 16];
#pragma unroll
        for (int u = 0; u < 8; ++u) w[u] = weights[r[u]];
#pragma unroll
        for (int u = 0; u < 8; ++u) f[u] = f4[(long)r[u] * 32 + lane32];
#pragma unroll
        for (int u = 0; u < 8; ++u) {
            acc.x += w[u] * f[u].x; acc.y += w[u] * f[u].y;
            acc.z += w[u] * f[u].z; acc.w += w[u] * f[u].w;
            wacc  += w[u];
        }
    }
    for (; i < n; i += 16) {
        unsigned r = perm[base + i];
        float w = weights[r];
        float4 f = f4[(long)r * 32 + lane32];
        acc.x += w * f.x; acc.y += w * f.y; acc.z += w * f.z; acc.w += w * f.w;
        wacc += w;
    }

    __shared__ float4 sAcc[16][32];
    __shared__ float  sW[16];
    sAcc[grp][lane32] = acc;
    if (lane32 == 0) sW[grp] = wacc;   // identical across lanes of the group
    __syncthreads();

    if (grp == 0) {
        float4 t = sAcc[0][lane32];
#pragma unroll
        for (int g = 1; g < 16; ++g) {
            float4 a = sAcc[g][lane32];
            t.x += a.x; t.y += a.y; t.z += a.z; t.w += a.w;
        }
        float ws = 0.f;
#pragma unroll
        for (int g = 0; g < 16; ++g) ws += sW[g];

        const float4 p = ((const float4*)proto)[c * 32 + lane32];
        float4 o;
        if (ws > 0.f) {
            const float den = fmaxf(ws, 1e-8f);
            o.x = MOM * p.x + 0.05f * (t.x / den);
            o.y = MOM * p.y + 0.05f * (t.y / den);
            o.z = MOM * p.z + 0.05f * (t.z / den);
            o.w = MOM * p.w + 0.05f * (t.w / den);
        } else {
            o = p;
        }
        ((float4*)out)[c * 32 + lane32] = o;
    }
}

extern "C" void kernel_launch(void* const* d_in, const int* in_sizes, int n_in,
                              void* d_out, int out_size, void* d_ws, size_t ws_size,
                              hipStream_t stream)
{
    const float* feats   = (const float*)d_in[0];
    const int*   labels  = (const int*)  d_in[1];
    const float* weights = (const float*)d_in[2];
    const float* proto   = (const float*)d_in[3];
    float* out = (float*)d_out;

    unsigned* total     = (unsigned*)d_ws;
    unsigned* classBase = total + 1024;
    unsigned* blockCnt  = classBase + 1024;           // 256*1024
    unsigned* blockBase = blockCnt + NBLK * 1024;     // 256*1024
    unsigned* perm      = blockBase + NBLK * 1024;    // NROWS

    hipMemsetAsync(total, 0, 1024 * sizeof(unsigned), stream);
    k_hist   <<<NBLK, 256, 0, stream>>>(labels, total, blockCnt);
    k_scan   <<<1, 1024, 0, stream>>>(total, classBase);
    k_scanB  <<<NCLS, 256, 0, stream>>>(blockCnt, classBase, blockBase);
    k_scatter<<<NBLK, 256, 0, stream>>>(labels, blockBase, perm);
    k_reduce <<<NCLS, 512, 0, stream>>>(feats, weights, proto, perm,
                                        total, classBase, out);
}

// Round 12
// 717.623 us; speedup vs baseline: 1.0165x; 1.0165x over previous
//
#include <hip/hip_runtime.h>

#define NROWS 1048576
#define DIM   128
#define NCLS  1000
#define NBLK  256           // hist/scatter blocks
#define RPB   4096          // rows per block in hist/scatter (NROWS/NBLK)
#define RPT   16            // rows per thread (RPB/256)
#define MOM   0.95f

// ws layout (u32):
//   total[1024] | classBase[1024] | blockCnt[256*1024] | blockBase[256*1024]
//   | perm[NROWS]   (~6.3 MB; only total[] needs zeroing per call)

// ---------------------------------------------------------------------------
// K1: per-block LDS histogram -> blockCnt[b][c] and global total[c]
// ---------------------------------------------------------------------------
__global__ __launch_bounds__(256) void k_hist(const int* __restrict__ labels,
                                              unsigned* __restrict__ total,
                                              unsigned* __restrict__ blockCnt)
{
    __shared__ unsigned h[1024];
    const int tid = threadIdx.x;
    const int b   = blockIdx.x;
    for (int c = tid; c < 1024; c += 256) h[c] = 0u;
    __syncthreads();
    const int base = b * RPB;
#pragma unroll
    for (int k = 0; k < RPT; ++k)
        atomicAdd(&h[labels[base + k * 256 + tid]], 1u);
    __syncthreads();
    for (int c = tid; c < 1024; c += 256) {
        const unsigned cnt = h[c];
        blockCnt[b * 1024 + c] = cnt;
        if (cnt) atomicAdd(&total[c], cnt);
    }
}

// ---------------------------------------------------------------------------
// K2: single-block exclusive scan over total -> classBase
// ---------------------------------------------------------------------------
__global__ __launch_bounds__(1024) void k_scan(const unsigned* __restrict__ total,
                                               unsigned* __restrict__ classBase)
{
    __shared__ unsigned s[1024];
    const int tid = threadIdx.x;
    unsigned v = (tid < NCLS) ? total[tid] : 0u;
    s[tid] = v;
    __syncthreads();
    for (int off = 1; off < 1024; off <<= 1) {
        unsigned u = (tid >= off) ? s[tid - off] : 0u;
        __syncthreads();
        s[tid] += u;
        __syncthreads();
    }
    if (tid < NCLS) classBase[tid] = s[tid] - v;   // exclusive prefix
}

// ---------------------------------------------------------------------------
// K2b: per-class scan across the 256 hist blocks ->
//      blockBase[b][c] = classBase[c] + sum_{b'<b} blockCnt[b'][c]
// ---------------------------------------------------------------------------
__global__ __launch_bounds__(256) void k_scanB(const unsigned* __restrict__ blockCnt,
                                               const unsigned* __restrict__ classBase,
                                               unsigned* __restrict__ blockBase)
{
    __shared__ unsigned s[256];
    const int c = blockIdx.x;
    const int t = threadIdx.x;
    unsigned v = blockCnt[t * 1024 + c];
    s[t] = v;
    __syncthreads();
    for (int off = 1; off < 256; off <<= 1) {
        unsigned u = (t >= off) ? s[t - off] : 0u;
        __syncthreads();
        s[t] += u;
        __syncthreads();
    }
    blockBase[t * 1024 + c] = classBase[c] + (s[t] - v);
}

// ---------------------------------------------------------------------------
// K3: staged scatter. Block-local counting sort in LDS (hist -> blocked
// scan -> bin), then pos-ordered writeout so destinations form sequential
// runs per class (~4x fewer write transactions than scattered 4B singles).
// ---------------------------------------------------------------------------
__global__ __launch_bounds__(256) void k_scatter(const int* __restrict__ labels,
                                                 const unsigned* __restrict__ blockBase,
                                                 unsigned* __restrict__ perm)
{
    __shared__ unsigned h[1024];           // counts, then reused as offsets
    __shared__ unsigned localBase[1024];
    __shared__ unsigned basec[1024];
    __shared__ unsigned tsum[256];
    __shared__ unsigned s_perm[RPB];       // 16 KB staging
    __shared__ unsigned short s_cls[RPB];  // 8 KB

    const int tid = threadIdx.x;
    const int b   = blockIdx.x;

    for (int c = tid; c < 1024; c += 256) {
        h[c]     = 0u;
        basec[c] = blockBase[b * 1024 + c];
    }
    __syncthreads();

    const int base = b * RPB;
    int lab[RPT];
#pragma unroll
    for (int k = 0; k < RPT; ++k) {
        lab[k] = labels[base + k * 256 + tid];
        atomicAdd(&h[lab[k]], 1u);
    }
    __syncthreads();

    // blocked exclusive scan over h[0..1023] -> localBase
    const unsigned a0 = h[4*tid], a1 = h[4*tid+1], a2 = h[4*tid+2], a3 = h[4*tid+3];
    const unsigned ts = a0 + a1 + a2 + a3;
    tsum[tid] = ts;
    __syncthreads();
    for (int off = 1; off < 256; off <<= 1) {
        unsigned u = (tid >= off) ? tsum[tid - off] : 0u;
        __syncthreads();
        tsum[tid] += u;
        __syncthreads();
    }
    const unsigned eb = tsum[tid] - ts;
    localBase[4*tid]   = eb;
    localBase[4*tid+1] = eb + a0;
    localBase[4*tid+2] = eb + a0 + a1;
    localBase[4*tid+3] = eb + a0 + a1 + a2;
    h[4*tid] = 0u; h[4*tid+1] = 0u; h[4*tid+2] = 0u; h[4*tid+3] = 0u;
    __syncthreads();

    // bin rows into LDS staging, ordered by class
#pragma unroll
    for (int k = 0; k < RPT; ++k) {
        const int c = lab[k];
        const unsigned pos = localBase[c] + atomicAdd(&h[c], 1u);
        s_perm[pos] = (unsigned)(base + k * 256 + tid);
        s_cls[pos]  = (unsigned short)c;
    }
    __syncthreads();

    // pos-ordered writeout: sequential runs per class
    for (int pos = tid; pos < RPB; pos += 256) {
        const int c = s_cls[pos];
        perm[basec[c] + (pos - localBase[c])] = s_perm[pos];
    }
}

// ---------------------------------------------------------------------------
// K4: one block (256 thr, 8 row-groups) per class. Gather rows via perm
// (contiguous 512B per row, 32 lanes x float4), 4 independent load chains,
// register accumulate, LDS tree reduce, fused EMA epilogue. No atomics.
// ---------------------------------------------------------------------------
__global__ __launch_bounds__(256) void k_reduce(
        const float*    __restrict__ feats,
        const float*    __restrict__ weights,
        const float*    __restrict__ proto,
        const unsigned* __restrict__ perm,
        const unsigned* __restrict__ total,
        const unsigned* __restrict__ classBase,
        float* __restrict__ out)
{
    const int c      = blockIdx.x;
    const int tid    = threadIdx.x;
    const int lane32 = tid & 31;
    const int grp    = tid >> 5;            // 0..7 row-groups
    const int n      = (int)total[c];
    const unsigned base = classBase[c];
    const float4* __restrict__ f4 = (const float4*)feats;

    float4 acc = make_float4(0.f, 0.f, 0.f, 0.f);
    float  wacc = 0.f;

    int i = grp;
    for (; i + 24 < n; i += 32) {
        unsigned r0 = perm[base + i];
        unsigned r1 = perm[base + i + 8];
        unsigned r2 = perm[base + i + 16];
        unsigned r3 = perm[base + i + 24];
        float w0 = weights[r0], w1 = weights[r1];
        float w2 = weights[r2], w3 = weights[r3];
        float4 f0 = f4[(long)r0 * 32 + lane32];
        float4 f1 = f4[(long)r1 * 32 + lane32];
        float4 f2 = f4[(long)r2 * 32 + lane32];
        float4 f3 = f4[(long)r3 * 32 + lane32];
        acc.x += w0 * f0.x; acc.y += w0 * f0.y; acc.z += w0 * f0.z; acc.w += w0 * f0.w;
        acc.x += w1 * f1.x; acc.y += w1 * f1.y; acc.z += w1 * f1.z; acc.w += w1 * f1.w;
        acc.x += w2 * f2.x; acc.y += w2 * f2.y; acc.z += w2 * f2.z; acc.w += w2 * f2.w;
        acc.x += w3 * f3.x; acc.y += w3 * f3.y; acc.z += w3 * f3.z; acc.w += w3 * f3.w;
        wacc += w0 + w1 + w2 + w3;
    }
    for (; i < n; i += 8) {
        unsigned r = perm[base + i];
        float w = weights[r];
        float4 f = f4[(long)r * 32 + lane32];
        acc.x += w * f.x; acc.y += w * f.y; acc.z += w * f.z; acc.w += w * f.w;
        wacc += w;
    }

    __shared__ float4 sAcc[8][32];
    __shared__ float  sW[8];
    sAcc[grp][lane32] = acc;
    if (lane32 == 0) sW[grp] = wacc;
    __syncthreads();

    if (grp == 0) {
        float4 t = sAcc[0][lane32];
#pragma unroll
        for (int g = 1; g < 8; ++g) {
            float4 a = sAcc[g][lane32];
            t.x += a.x; t.y += a.y; t.z += a.z; t.w += a.w;
        }
        float ws = 0.f;
#pragma unroll
        for (int g = 0; g < 8; ++g) ws += sW[g];

        const float4 p = ((const float4*)proto)[c * 32 + lane32];
        float4 o;
        if (ws > 0.f) {
            const float den = fmaxf(ws, 1e-8f);
            o.x = MOM * p.x + 0.05f * (t.x / den);
            o.y = MOM * p.y + 0.05f * (t.y / den);
            o.z = MOM * p.z + 0.05f * (t.z / den);
            o.w = MOM * p.w + 0.05f * (t.w / den);
        } else {
            o = p;
        }
        ((float4*)out)[c * 32 + lane32] = o;
    }
}

extern "C" void kernel_launch(void* const* d_in, const int* in_sizes, int n_in,
                              void* d_out, int out_size, void* d_ws, size_t ws_size,
                              hipStream_t stream)
{
    const float* feats   = (const float*)d_in[0];
    const int*   labels  = (const int*)  d_in[1];
    const float* weights = (const float*)d_in[2];
    const float* proto   = (const float*)d_in[3];
    float* out = (float*)d_out;

    unsigned* total     = (unsigned*)d_ws;
    unsigned* classBase = total + 1024;
    unsigned* blockCnt  = classBase + 1024;           // 256*1024
    unsigned* blockBase = blockCnt + NBLK * 1024;     // 256*1024
    unsigned* perm      = blockBase + NBLK * 1024;    // NROWS

    hipMemsetAsync(total, 0, 1024 * sizeof(unsigned), stream);
    k_hist   <<<NBLK, 256, 0, stream>>>(labels, total, blockCnt);
    k_scan   <<<1, 1024, 0, stream>>>(total, classBase);
    k_scanB  <<<NCLS, 256, 0, stream>>>(blockCnt, classBase, blockBase);
    k_scatter<<<NBLK, 256, 0, stream>>>(labels, blockBase, perm);
    k_reduce <<<NCLS, 256, 0, stream>>>(feats, weights, proto, perm,
                                        total, classBase, out);
}

// Round 13
// 710.257 us; speedup vs baseline: 1.0270x; 1.0104x over previous
//
#include <hip/hip_runtime.h>

#define NROWS 1048576
#define DIM   128
#define NCLS  1000
#define NBLK  256           // hist/scatter blocks
#define RPB   4096          // rows per block (NROWS/NBLK)
#define RPT   16            // rows per thread (RPB/256)
#define MOM   0.95f

// ws layout (u32):
//   total[1024] | classBase[1024] | blockCntT[1024*256] | blockBaseT[1024*256]
//   | perm[NROWS]   (~6.3 MB; only total[] needs zeroing per call)

// ---------------------------------------------------------------------------
// K1: per-block LDS histogram -> blockCntT[c][b] (transposed) + total[c].
// Each thread owns 16 consecutive rows (4 x int4 label loads).
// ---------------------------------------------------------------------------
__global__ __launch_bounds__(256) void k_hist(const int* __restrict__ labels,
                                              unsigned* __restrict__ total,
                                              unsigned* __restrict__ blockCntT)
{
    __shared__ unsigned h[1024];
    const int tid = threadIdx.x;
    const int b   = blockIdx.x;
    for (int c = tid; c < 1024; c += 256) h[c] = 0u;
    __syncthreads();
    const int rbase = b * RPB + tid * RPT;
    const int4* __restrict__ l4 = (const int4*)(labels + rbase);
#pragma unroll
    for (int k = 0; k < 4; ++k) {
        const int4 v = l4[k];
        atomicAdd(&h[v.x], 1u); atomicAdd(&h[v.y], 1u);
        atomicAdd(&h[v.z], 1u); atomicAdd(&h[v.w], 1u);
    }
    __syncthreads();
    for (int c = tid; c < 1024; c += 256) {
        const unsigned cnt = h[c];
        blockCntT[c * NBLK + b] = cnt;
        if (cnt) atomicAdd(&total[c], cnt);
    }
}

// ---------------------------------------------------------------------------
// K2: one block per class. classBase[c] = masked reduction over total[0..c);
// then coalesced 256-scan of blockCntT[c][:] -> blockBaseT[c][b].
// Replaces the old k_scan + k_scanB pair (one fewer dispatch, coalesced).
// ---------------------------------------------------------------------------
__global__ __launch_bounds__(256) void k_bases(const unsigned* __restrict__ total,
                                               const unsigned* __restrict__ blockCntT,
                                               unsigned* __restrict__ classBase,
                                               unsigned* __restrict__ blockBaseT)
{
    const int c = blockIdx.x;
    const int t = threadIdx.x;
    __shared__ unsigned sred[8];
    __shared__ unsigned sscan[256];

    // classBase[c] = sum_{j<c} total[j]
    unsigned partial = 0;
#pragma unroll
    for (int k = 0; k < 4; ++k) {
        const int j = t * 4 + k;
        if (j < c) partial += total[j];
    }
#pragma unroll
    for (int off = 32; off; off >>= 1) partial += __shfl_down(partial, off);
    if ((t & 63) == 0) sred[t >> 6] = partial;
    __syncthreads();
    if (t == 0) sred[4] = sred[0] + sred[1] + sred[2] + sred[3];
    __syncthreads();
    const unsigned cb = sred[4];

    // exclusive 256-scan of this class's per-block counts (contiguous 1KB)
    const unsigned v = blockCntT[c * NBLK + t];
    sscan[t] = v;
    __syncthreads();
    for (int off = 1; off < 256; off <<= 1) {
        unsigned u = (t >= off) ? sscan[t - off] : 0u;
        __syncthreads();
        sscan[t] += u;
        __syncthreads();
    }
    blockBaseT[c * NBLK + t] = cb + (sscan[t] - v);
    if (t == 0) classBase[c] = cb;
}

// ---------------------------------------------------------------------------
// K3: staged scatter (block-local LDS counting sort -> pos-ordered writeout).
// basec reads are stride-256 words but L2-served (blockBaseT is 1 MB hot).
// ---------------------------------------------------------------------------
__global__ __launch_bounds__(256) void k_scatter(const int* __restrict__ labels,
                                                 const unsigned* __restrict__ blockBaseT,
                                                 unsigned* __restrict__ perm)
{
    __shared__ unsigned h[1024];           // counts, then reused as offsets
    __shared__ unsigned localBase[1024];
    __shared__ unsigned basec[1024];
    __shared__ unsigned tsum[256];
    __shared__ unsigned s_perm[RPB];       // 16 KB staging
    __shared__ unsigned short s_cls[RPB];  // 8 KB

    const int tid = threadIdx.x;
    const int b   = blockIdx.x;

    for (int c = tid; c < 1024; c += 256) {
        h[c]     = 0u;
        basec[c] = blockBaseT[c * NBLK + b];
    }
    __syncthreads();

    const int rbase = b * RPB + tid * RPT;
    const int4* __restrict__ l4 = (const int4*)(labels + rbase);
    int lab[RPT];
#pragma unroll
    for (int k = 0; k < 4; ++k) {
        const int4 v = l4[k];
        lab[4*k] = v.x; lab[4*k+1] = v.y; lab[4*k+2] = v.z; lab[4*k+3] = v.w;
    }
#pragma unroll
    for (int k = 0; k < RPT; ++k) atomicAdd(&h[lab[k]], 1u);
    __syncthreads();

    // blocked exclusive scan over h[0..1023] -> localBase
    const unsigned a0 = h[4*tid], a1 = h[4*tid+1], a2 = h[4*tid+2], a3 = h[4*tid+3];
    const unsigned ts = a0 + a1 + a2 + a3;
    tsum[tid] = ts;
    __syncthreads();
    for (int off = 1; off < 256; off <<= 1) {
        unsigned u = (tid >= off) ? tsum[tid - off] : 0u;
        __syncthreads();
        tsum[tid] += u;
        __syncthreads();
    }
    const unsigned eb = tsum[tid] - ts;
    localBase[4*tid]   = eb;
    localBase[4*tid+1] = eb + a0;
    localBase[4*tid+2] = eb + a0 + a1;
    localBase[4*tid+3] = eb + a0 + a1 + a2;
    h[4*tid] = 0u; h[4*tid+1] = 0u; h[4*tid+2] = 0u; h[4*tid+3] = 0u;
    __syncthreads();

    // bin rows into LDS staging, ordered by class
#pragma unroll
    for (int k = 0; k < RPT; ++k) {
        const int c = lab[k];
        const unsigned pos = localBase[c] + atomicAdd(&h[c], 1u);
        s_perm[pos] = (unsigned)(rbase + k);
        s_cls[pos]  = (unsigned short)c;
    }
    __syncthreads();

    // pos-ordered writeout: sequential runs per class
    for (int pos = tid; pos < RPB; pos += 256) {
        const int c = s_cls[pos];
        perm[basec[c] + (pos - localBase[c])] = s_perm[pos];
    }
}

// ---------------------------------------------------------------------------
// K4: one block (256 thr, 8 row-groups) per class. Gather rows via perm
// (contiguous 512B per row, 32 lanes x float4), 4 independent load chains,
// register accumulate, LDS tree reduce, fused EMA epilogue. No atomics.
// ---------------------------------------------------------------------------
__global__ __launch_bounds__(256) void k_reduce(
        const float*    __restrict__ feats,
        const float*    __restrict__ weights,
        const float*    __restrict__ proto,
        const unsigned* __restrict__ perm,
        const unsigned* __restrict__ total,
        const unsigned* __restrict__ classBase,
        float* __restrict__ out)
{
    const int c      = blockIdx.x;
    const int tid    = threadIdx.x;
    const int lane32 = tid & 31;
    const int grp    = tid >> 5;            // 0..7 row-groups
    const int n      = (int)total[c];
    const unsigned base = classBase[c];
    const float4* __restrict__ f4 = (const float4*)feats;

    float4 acc = make_float4(0.f, 0.f, 0.f, 0.f);
    float  wacc = 0.f;

    int i = grp;
    for (; i + 24 < n; i += 32) {
        unsigned r0 = perm[base + i];
        unsigned r1 = perm[base + i + 8];
        unsigned r2 = perm[base + i + 16];
        unsigned r3 = perm[base + i + 24];
        float w0 = weights[r0], w1 = weights[r1];
        float w2 = weights[r2], w3 = weights[r3];
        float4 f0 = f4[(long)r0 * 32 + lane32];
        float4 f1 = f4[(long)r1 * 32 + lane32];
        float4 f2 = f4[(long)r2 * 32 + lane32];
        float4 f3 = f4[(long)r3 * 32 + lane32];
        acc.x += w0 * f0.x; acc.y += w0 * f0.y; acc.z += w0 * f0.z; acc.w += w0 * f0.w;
        acc.x += w1 * f1.x; acc.y += w1 * f1.y; acc.z += w1 * f1.z; acc.w += w1 * f1.w;
        acc.x += w2 * f2.x; acc.y += w2 * f2.y; acc.z += w2 * f2.z; acc.w += w2 * f2.w;
        acc.x += w3 * f3.x; acc.y += w3 * f3.y; acc.z += w3 * f3.z; acc.w += w3 * f3.w;
        wacc += w0 + w1 + w2 + w3;
    }
    for (; i < n; i += 8) {
        unsigned r = perm[base + i];
        float w = weights[r];
        float4 f = f4[(long)r * 32 + lane32];
        acc.x += w * f.x; acc.y += w * f.y; acc.z += w * f.z; acc.w += w * f.w;
        wacc += w;
    }

    __shared__ float4 sAcc[8][32];
    __shared__ float  sW[8];
    sAcc[grp][lane32] = acc;
    if (lane32 == 0) sW[grp] = wacc;
    __syncthreads();

    if (grp == 0) {
        float4 t = sAcc[0][lane32];
#pragma unroll
        for (int g = 1; g < 8; ++g) {
            float4 a = sAcc[g][lane32];
            t.x += a.x; t.y += a.y; t.z += a.z; t.w += a.w;
        }
        float ws = 0.f;
#pragma unroll
        for (int g = 0; g < 8; ++g) ws += sW[g];

        const float4 p = ((const float4*)proto)[c * 32 + lane32];
        float4 o;
        if (ws > 0.f) {
            const float den = fmaxf(ws, 1e-8f);
            o.x = MOM * p.x + 0.05f * (t.x / den);
            o.y = MOM * p.y + 0.05f * (t.y / den);
            o.z = MOM * p.z + 0.05f * (t.z / den);
            o.w = MOM * p.w + 0.05f * (t.w / den);
        } else {
            o = p;
        }
        ((float4*)out)[c * 32 + lane32] = o;
    }
}

extern "C" void kernel_launch(void* const* d_in, const int* in_sizes, int n_in,
                              void* d_out, int out_size, void* d_ws, size_t ws_size,
                              hipStream_t stream)
{
    const float* feats   = (const float*)d_in[0];
    const int*   labels  = (const int*)  d_in[1];
    const float* weights = (const float*)d_in[2];
    const float* proto   = (const float*)d_in[3];
    float* out = (float*)d_out;

    unsigned* total      = (unsigned*)d_ws;
    unsigned* classBase  = total + 1024;
    unsigned* blockCntT  = classBase + 1024;            // 1024*256
    unsigned* blockBaseT = blockCntT + 1024 * NBLK;     // 1024*256
    unsigned* perm       = blockBaseT + 1024 * NBLK;    // NROWS

    hipMemsetAsync(total, 0, 1024 * sizeof(unsigned), stream);
    k_hist   <<<NBLK, 256, 0, stream>>>(labels, total, blockCntT);
    k_bases  <<<NCLS, 256, 0, stream>>>(total, blockCntT, classBase, blockBaseT);
    k_scatter<<<NBLK, 256, 0, stream>>>(labels, blockBaseT, perm);
    k_reduce <<<NCLS, 256, 0, stream>>>(feats, weights, proto, perm,
                                        total, classBase, out);
}